// Round 10
// baseline (150.330 us; speedup 1.0000x reference)
//
#include <hip/hip_runtime.h>
#include <hip/hip_bf16.h>
#include <hip/hip_fp16.h>

#define NN 1024   // nodes
#define FD 64     // feature dim (in == out)
#define BB 32     // batch

typedef __attribute__((ext_vector_type(4))) float    f32x4;
typedef __attribute__((ext_vector_type(8))) _Float16 f16x8;

static __device__ __forceinline__ unsigned short f2hu(float x) {
  _Float16 h = (_Float16)x;
  return __builtin_bit_cast(unsigned short, h);
}
static __device__ __forceinline__ f16x8 bch(int4 v) {
  return __builtin_bit_cast(f16x8, v);
}
// async global->LDS DMA, 16B per lane, dest = ldsbase + lane*16 (HW rule)
static __device__ __forceinline__ void gld16(const void* g, void* l) {
  __builtin_amdgcn_global_load_lds(
      (const __attribute__((address_space(1))) void*)g,
      (__attribute__((address_space(3))) void*)l, 16, 0, 0);
}

// ---------------- Kernel 1 (validated R9): h = x@W fp32, f, g,
// hF = h^T in MFMA B-fragment order: int4 unit ((b*16+jt)*8 + frag)*64 + lane
__global__ __launch_bounds__(256) void gat_k1(
    const float* __restrict__ x, const float* __restrict__ W,
    const float* __restrict__ av, float* __restrict__ fv,
    float* __restrict__ gv, unsigned short* __restrict__ hF)
{
  __shared__ __align__(16) float Wl[FD * FD];
  __shared__ __align__(16) float xl[FD * 68];
  __shared__ __align__(16) unsigned short tl[FD * 64];
  __shared__ __align__(16) float al[2 * FD];

  const int tid = threadIdx.x;
  const int b   = blockIdx.x >> 4;
  const int n0  = (blockIdx.x & 15) << 6;

  if (tid < 32) ((f32x4*)al)[tid] = ((const f32x4*)av)[tid];
  {
    const int r  = tid >> 2;
    const int cb = (tid & 3) << 2;
    const f32x4* Wg = (const f32x4*)W;
    const f32x4* xg = (const f32x4*)(x + ((size_t)(b * NN + n0)) * FD);
#pragma unroll
    for (int k = 0; k < 4; ++k) {
      f32x4 wv = Wg[r * 16 + cb + k];
      f32x4 xv = xg[r * 16 + cb + k];
      *(f32x4*)(Wl + r * FD + ((cb + k) << 2)) = wv;
      *(f32x4*)(xl + r * 68 + ((cb + k) << 2)) = xv;
    }
  }
  __syncthreads();

  const int r  = tid >> 2;
  const int o0 = (tid & 3) << 4;
  float acc[16];
#pragma unroll
  for (int i = 0; i < 16; ++i) acc[i] = 0.f;

#pragma unroll 8
  for (int f = 0; f < FD; ++f) {
    float xv = xl[r * 68 + f];
    const f32x4* wr = (const f32x4*)(Wl + f * FD + o0);
#pragma unroll
    for (int c = 0; c < 4; ++c) {
      f32x4 wv = wr[c];
      acc[c * 4 + 0] += xv * wv.x;
      acc[c * 4 + 1] += xv * wv.y;
      acc[c * 4 + 2] += xv * wv.z;
      acc[c * 4 + 3] += xv * wv.w;
    }
  }

  float fp = 0.f, gp = 0.f;
#pragma unroll
  for (int i = 0; i < 16; ++i) {
    fp += acc[i] * al[o0 + i];
    gp += acc[i] * al[FD + o0 + i];
  }
  fp += __shfl_xor(fp, 1); fp += __shfl_xor(fp, 2);
  gp += __shfl_xor(gp, 1); gp += __shfl_xor(gp, 2);
  if ((tid & 3) == 0) {
    fv[b * NN + n0 + r] = fp;
    gv[b * NN + n0 + r] = gp;
  }

#pragma unroll
  for (int i = 0; i < 16; ++i) {
    int o = o0 + i;
    tl[o * 64 + ((((r >> 3) ^ (o & 7)) << 3) | (r & 7))] = f2hu(acc[i]);
  }
  __syncthreads();
  {
    const int jt = n0 >> 6;
#pragma unroll
    for (int hh = 0; hh < 2; ++hh) {
      int u = tid + (hh << 8);
      int frag = u >> 6, l = u & 63;
      int o = ((frag >> 1) << 4) + (l & 15);
      int c = ((frag & 1) << 2) + (l >> 4);
      int4 v = *(const int4*)(tl + o * 64 + ((c ^ (o & 7)) << 3));
      *(int4*)(hF + ((((size_t)(b * 16 + jt)) * 8 + frag) * 64 + l) * 8) = v;
    }
  }
}

// ---------------- Kernel 2: masked-softmax attention + PV (MFMA f16) + elu
// 1024 blocks x 2 waves (wave = 16 rows x all 1024 cols). Staging via
// global_load_lds DMA (zero VGPR cost -> compiler cannot serialize the
// prefetch). Triple-buffered LDS, distance-2, counted vmcnt(8), raw
// s_barrier (no vmcnt drain).
__global__ __launch_bounds__(128) void gat_k2(
    const int* __restrict__ adj, const float* __restrict__ fv,
    const float* __restrict__ gv, const unsigned short* __restrict__ hF,
    float* __restrict__ out)
{
  __shared__ __align__(16) char stg[3][16384]; // [adj w0|adj w1|hF f0-7] 48 KB
  __shared__ __align__(16) float gl[NN];       // 4 KB
  __shared__ float red[2];

  const int tid  = threadIdx.x;
  const int b    = blockIdx.x >> 5;
  const int i0   = (blockIdx.x & 31) << 5;
  const int lane = tid & 63, w = tid >> 6;
  const int m16  = lane & 15, hi = lane >> 4;
  const int bN   = b * NN;

  // ---- prologue: stage g into LDS, block shift Cb (uses __syncthreads;
  // its vmcnt(0) drain is harmless here, pipeline not started yet)
  {
    f32x4 ga = ((const f32x4*)(gv + bN))[tid * 2];
    f32x4 gb = ((const f32x4*)(gv + bN))[tid * 2 + 1];
    ((f32x4*)gl)[tid * 2]     = ga;
    ((f32x4*)gl)[tid * 2 + 1] = gb;
    float gm = fmaxf(fmaxf(fmaxf(ga.x, ga.y), fmaxf(ga.z, ga.w)),
                     fmaxf(fmaxf(gb.x, gb.y), fmaxf(gb.z, gb.w)));
    float fm = fv[bN + i0 + (tid & 31)];
#pragma unroll
    for (int m = 1; m < 64; m <<= 1) {
      gm = fmaxf(gm, __shfl_xor(gm, m));
      fm = fmaxf(fm, __shfl_xor(fm, m));
    }
    if (lane == 0) red[w] = gm;
    const float frt = fv[bN + i0 + w * 16 + m16];   // issue before sync
    __syncthreads();
    gm = fmaxf(red[0], red[1]);
    const float sm = fm + gm;
    const float Cb_ = fmaxf(sm, 0.2f * sm);
    // keep in named vars below
    red[0] = red[0];  // no-op
    // fall through with frt/Cb_ captured:
    // (use locals declared after)
    #define FR frt
    #define CBV Cb_

  const int*  adjR = adj + ((size_t)(bN + i0 + w * 16 + m16)) * NN + hi * 8;
  const int4* hFb  = (const int4*)hF + ((size_t)b * 16 * 8) * 64 + lane;

  float dAcc = 0.f;
  f32x4 acc[4];
#pragma unroll
  for (int n = 0; n < 4; ++n) acc[n] = (f32x4){0.f, 0.f, 0.f, 0.f};

  // per-wave DMA: 4 adj chunks (its 16 rows) + 4 hF frags (w*4..w*4+3)
#define STAGE(jt, p) do {                                                  \
    const int* ga_ = adjR + (jt) * 64;                                     \
    char* la_ = stg[p] + w * 4096;                                         \
    gld16(ga_,      la_);                                                  \
    gld16(ga_ + 4,  la_ + 1024);                                           \
    gld16(ga_ + 32, la_ + 2048);                                           \
    gld16(ga_ + 36, la_ + 3072);                                           \
    const int4* gh_ = hFb + ((size_t)(jt) * 8 + w * 4) * 64;               \
    char* lh_ = stg[p] + 8192 + w * 4096;                                  \
    gld16(gh_,       lh_);                                                 \
    gld16(gh_ + 64,  lh_ + 1024);                                          \
    gld16(gh_ + 128, lh_ + 2048);                                          \
    gld16(gh_ + 192, lh_ + 3072);                                          \
  } while (0)

#define PCOMP(dst, ia, ib, ga, gb) do {                                    \
    float e0 = FR + ga.x, e1 = FR + ga.y, e2 = FR + ga.z, e3 = FR + ga.w;  \
    float e4 = FR + gb.x, e5 = FR + gb.y, e6 = FR + gb.z, e7 = FR + gb.w;  \
    e0 = fmaxf(e0, 0.2f * e0) - CBV; e1 = fmaxf(e1, 0.2f * e1) - CBV;      \
    e2 = fmaxf(e2, 0.2f * e2) - CBV; e3 = fmaxf(e3, 0.2f * e3) - CBV;      \
    e4 = fmaxf(e4, 0.2f * e4) - CBV; e5 = fmaxf(e5, 0.2f * e5) - CBV;      \
    e6 = fmaxf(e6, 0.2f * e6) - CBV; e7 = fmaxf(e7, 0.2f * e7) - CBV;      \
    float p0 = (ia.x > 0) ? __expf(e0) : 0.f;                              \
    float p1 = (ia.y > 0) ? __expf(e1) : 0.f;                              \
    float p2 = (ia.z > 0) ? __expf(e2) : 0.f;                              \
    float p3 = (ia.w > 0) ? __expf(e3) : 0.f;                              \
    float p4 = (ib.x > 0) ? __expf(e4) : 0.f;                              \
    float p5 = (ib.y > 0) ? __expf(e5) : 0.f;                              \
    float p6 = (ib.z > 0) ? __expf(e6) : 0.f;                              \
    float p7 = (ib.w > 0) ? __expf(e7) : 0.f;                              \
    dAcc += ((p0 + p1) + (p2 + p3)) + ((p4 + p5) + (p6 + p7));             \
    dst = (f16x8){(_Float16)p0, (_Float16)p1, (_Float16)p2, (_Float16)p3,  \
                  (_Float16)p4, (_Float16)p5, (_Float16)p6, (_Float16)p7}; \
  } while (0)

  STAGE(0, 0);
  STAGE(1, 1);

#pragma unroll
  for (int t = 0; t < 16; ++t) {
    if (t < 15) { asm volatile("s_waitcnt vmcnt(8)" ::: "memory"); }
    else        { asm volatile("s_waitcnt vmcnt(0)" ::: "memory"); }
    __builtin_amdgcn_sched_barrier(0);
    __builtin_amdgcn_s_barrier();
    __builtin_amdgcn_sched_barrier(0);
    const int p = t % 3;
    const char* sa = stg[p] + w * 4096 + lane * 16;
    int4 a0 = *(const int4*)(sa);
    int4 a1 = *(const int4*)(sa + 1024);
    int4 a2 = *(const int4*)(sa + 2048);
    int4 a3 = *(const int4*)(sa + 3072);
    const char* sh = stg[p] + 8192 + lane * 16;
    int4 h0 = *(const int4*)(sh);
    int4 h1 = *(const int4*)(sh + 1024);
    int4 h2 = *(const int4*)(sh + 2048);
    int4 h3 = *(const int4*)(sh + 3072);
    int4 h4 = *(const int4*)(sh + 4096);
    int4 h5 = *(const int4*)(sh + 5120);
    int4 h6 = *(const int4*)(sh + 6144);
    int4 h7 = *(const int4*)(sh + 7168);
    const float* gp_ = gl + t * 64 + hi * 8;
    f32x4 ga0 = *(const f32x4*)(gp_);
    f32x4 ga1 = *(const f32x4*)(gp_ + 4);
    f32x4 gb0 = *(const f32x4*)(gp_ + 32);
    f32x4 gb1 = *(const f32x4*)(gp_ + 36);
    f16x8 pa, pb;
    PCOMP(pa, a0, a1, ga0, ga1);
    PCOMP(pb, a2, a3, gb0, gb1);
    acc[0] = __builtin_amdgcn_mfma_f32_16x16x32_f16(pa, bch(h0), acc[0], 0, 0, 0);
    acc[0] = __builtin_amdgcn_mfma_f32_16x16x32_f16(pb, bch(h1), acc[0], 0, 0, 0);
    acc[1] = __builtin_amdgcn_mfma_f32_16x16x32_f16(pa, bch(h2), acc[1], 0, 0, 0);
    acc[1] = __builtin_amdgcn_mfma_f32_16x16x32_f16(pb, bch(h3), acc[1], 0, 0, 0);
    acc[2] = __builtin_amdgcn_mfma_f32_16x16x32_f16(pa, bch(h4), acc[2], 0, 0, 0);
    acc[2] = __builtin_amdgcn_mfma_f32_16x16x32_f16(pb, bch(h5), acc[2], 0, 0, 0);
    acc[3] = __builtin_amdgcn_mfma_f32_16x16x32_f16(pa, bch(h6), acc[3], 0, 0, 0);
    acc[3] = __builtin_amdgcn_mfma_f32_16x16x32_f16(pb, bch(h7), acc[3], 0, 0, 0);
    if (t < 14) STAGE(t + 2, (t + 2) % 3);
  }
#undef STAGE
#undef PCOMP

  // denominator: combine 4 hi-groups per row (full row lives in this wave)
  dAcc += __shfl_xor(dAcc, 16);
  dAcc += __shfl_xor(dAcc, 32);

  float* outB = out + ((size_t)(bN + i0 + w * 16)) * FD;
#pragma unroll
  for (int rr = 0; rr < 4; ++rr) {
    const int lr = hi * 4 + rr;           // local row (C/D layout)
    float d   = __shfl(dAcc, lr);
    float inv = d > 0.f ? 1.f / d : 0.f;
#pragma unroll
    for (int n = 0; n < 4; ++n) {
      float v = acc[n][rr] * inv;
      v = v > 0.f ? v : (__expf(v) - 1.f);  // elu (alpha=1)
      outB[(size_t)lr * FD + n * 16 + m16] = v;
    }
  }
#undef FR
#undef CBV
  }
}

extern "C" void kernel_launch(void* const* d_in, const int* in_sizes, int n_in,
                              void* d_out, int out_size, void* d_ws, size_t ws_size,
                              hipStream_t stream) {
  const float* x   = (const float*)d_in[0];
  const int*   adj = (const int*)d_in[1];
  const float* W   = (const float*)d_in[2];
  const float* a   = (const float*)d_in[3];
  float* out = (float*)d_out;

  // workspace: hF fp16 fragment-ordered (4 MB) | fv (128 KB) | gv (128 KB)
  unsigned short* hF = (unsigned short*)d_ws;
  float* fv = (float*)((char*)d_ws + (size_t)BB * FD * NN * 2);
  float* gv = fv + (size_t)BB * NN;

  gat_k1<<<dim3(BB * 16), dim3(256), 0, stream>>>(x, W, a, fv, gv, hF);
  gat_k2<<<dim3(BB * 32), dim3(128), 0, stream>>>(adj, fv, gv, hF, out);
}